// Round 1
// baseline (717.895 us; speedup 1.0000x reference)
//
#include <hip/hip_runtime.h>

#define DI __device__ __forceinline__

typedef float f32x4 __attribute__((ext_vector_type(4)));
typedef float f4    __attribute__((ext_vector_type(4)));
typedef _Float16 h8 __attribute__((ext_vector_type(8)));
typedef _Float16 h4 __attribute__((ext_vector_type(4)));

// sizes
#define SEQL 512
#define BATCH 256
#define INF 300
#define HID 256
#define N2 512   // 2*HID
#define KP 320   // INF padded to multiple of 64

DI float ftanh(float x) {
    float e = __expf(2.0f * x);
    return 1.0f - 2.0f / (e + 1.0f);
}

// ---------------- prep: build WcatT (pre-swizzled, f16) + bcat ----------------
// WTs[j][z] holds WcatT[j][k] with z = k ^ ((j&7)<<3)  (XOR confined to bits 3..5)
__global__ void prep_kernel(const float* __restrict__ W1x, const float* __restrict__ W2x,
                            const float* __restrict__ b1, const float* __restrict__ b2,
                            _Float16* __restrict__ WTs, float* __restrict__ bcat)
{
    int idx = blockIdx.x * 256 + threadIdx.x;
    if (idx < N2 * KP) {
        int j = idx / KP, z = idx - j * KP;
        int k = z ^ ((j & 7) << 3);
        float v = 0.f;
        if (k < INF) v = (j < HID) ? W1x[k * HID + j] : W2x[k * HID + (j - HID)];
        WTs[j * KP + z] = (_Float16)v;
    }
    if (idx < N2) bcat[idx] = (idx < HID) ? b1[idx] : b2[idx - HID];
}

// ---------------- GEMM: pre[t*B+b][j] = x[t,b,:] @ Wcat[:,j] + bcat[j] ----------------
// 128x128 tile, BK=64, 4 waves (2x2 of 64x64), fp16 MFMA, f32 acc, store f16.
__global__ __launch_bounds__(256, 2) void gemm_pre(
    const float* __restrict__ x, const _Float16* __restrict__ WTs,
    const float* __restrict__ bcat, _Float16* __restrict__ pre)
{
    __shared__ _Float16 Ab[128 * 64];
    __shared__ _Float16 Bb[128 * 64];
    const int tid = threadIdx.x;
    const int w = tid >> 6, l = tid & 63;
    const int lj = l & 15, lg = l >> 4;
    const int bm = blockIdx.x >> 2, bn = blockIdx.x & 3;
    const size_t m0 = (size_t)bm * 128;
    const int j0 = bn * 128;
    const int wm = (w >> 1) * 64, wn = (w & 1) * 64;

    f32x4 acc[4][4];
#pragma unroll
    for (int a = 0; a < 4; ++a)
#pragma unroll
        for (int b = 0; b < 4; ++b) acc[a][b] = f32x4{0.f, 0.f, 0.f, 0.f};

    float bias[4];
#pragma unroll
    for (int nt = 0; nt < 4; ++nt) bias[nt] = bcat[j0 + wn + nt * 16 + lj];

    for (int s = 0; s < 5; ++s) {
        const int k0 = s * 64;
        // B tile: global_load_lds (source pre-swizzled by prep) -> linear LDS
#pragma unroll
        for (int q = 0; q < 4; ++q) {
            int idx = (w * 4 + q) * 64 + l;
            int jr = idx >> 3, sl = idx & 7;
            const _Float16* src = WTs + (size_t)(j0 + jr) * KP + k0 + sl * 8;
            _Float16* dst = &Bb[(w * 4 + q) * 512];  // wave-uniform base
            __builtin_amdgcn_global_load_lds(
                (const __attribute__((address_space(1))) void*)src,
                (__attribute__((address_space(3))) void*)dst, 16, 0, 0);
        }
        // A tile: f32 load -> f16 convert -> swizzled ds_write
#pragma unroll
        for (int c = 0; c < 8; ++c) {
            int f = c * 256 + tid;
            int mr = f >> 4, k4 = f & 15;
            f4 v;
            if (k0 + k4 * 4 + 3 < INF)
                v = *(const f4*)(x + (m0 + mr) * INF + k0 + k4 * 4);
            else
                v = f4{0.f, 0.f, 0.f, 0.f};
            unsigned bo = (unsigned)mr * 128 + (((unsigned)k4 * 8) ^ ((mr & 7) << 4));
            *(h4*)((char*)Ab + bo) = h4{(_Float16)v[0], (_Float16)v[1], (_Float16)v[2], (_Float16)v[3]};
        }
        __syncthreads();
#pragma unroll
        for (int kk = 0; kk < 2; ++kk) {
            h8 af[4], bf[4];
#pragma unroll
            for (int mt = 0; mt < 4; ++mt) {
                int mr = wm + mt * 16 + lj;
                unsigned bo = (unsigned)mr * 128 + (((unsigned)(kk * 64 + lg * 16)) ^ ((mr & 7) << 4));
                af[mt] = *(const h8*)((const char*)Ab + bo);
            }
#pragma unroll
            for (int nt = 0; nt < 4; ++nt) {
                int jr = wn + nt * 16 + lj;
                unsigned bo = (unsigned)jr * 128 + (((unsigned)(kk * 64 + lg * 16)) ^ ((jr & 7) << 4));
                bf[nt] = *(const h8*)((const char*)Bb + bo);
            }
#pragma unroll
            for (int mt = 0; mt < 4; ++mt)
#pragma unroll
                for (int nt = 0; nt < 4; ++nt)
                    acc[mt][nt] = __builtin_amdgcn_mfma_f32_16x16x32_f16(af[mt], bf[nt], acc[mt][nt], 0, 0, 0);
        }
        __syncthreads();
    }
    // store C (+bias) as f16
#pragma unroll
    for (int mt = 0; mt < 4; ++mt) {
#pragma unroll
        for (int nt = 0; nt < 4; ++nt) {
            int jc = j0 + wn + nt * 16 + lj;
#pragma unroll
            for (int i = 0; i < 4; ++i) {
                size_t r = m0 + wm + mt * 16 + lg * 4 + i;
                pre[r * N2 + jc] = (_Float16)(acc[mt][nt][i] + bias[nt]);
            }
        }
    }
}

// ---------------- recurrence: 32 blocks = 16 b-tiles x 2 dirs, 8 waves each ----------------
// h' = tanh(pre[t] + h @ Wh). h kept in LDS (f16, XOR-swizzled), double-buffered.
__global__ __launch_bounds__(512, 2) void rnn_scan(
    const float* __restrict__ W1h, const float* __restrict__ W2h,
    const _Float16* __restrict__ pre, float* __restrict__ hcat)
{
    __shared__ _Float16 hb[2][16 * 256];
    const int tid = threadIdx.x;
    const int w = tid >> 6, l = tid & 63;
    const int lj = l & 15, lg = l >> 4;
    const int dir = blockIdx.x & 1;
    const int b0 = (int)(blockIdx.x >> 1) * 16;
    const float* Wh = dir ? W2h : W1h;
    const int j0 = w * 32;

    // Wh column fragments (B-operand), constant across all 512 steps: 64 VGPRs
    h8 bfrag[2][8];
#pragma unroll
    for (int jt = 0; jt < 2; ++jt) {
        int jc = j0 + jt * 16 + lj;
#pragma unroll
        for (int kk = 0; kk < 8; ++kk) {
            h8 t;
#pragma unroll
            for (int i = 0; i < 8; ++i) t[i] = (_Float16)Wh[(kk * 32 + lg * 8 + i) * HID + jc];
            bfrag[jt][kk] = t;
        }
    }
    // zero h buffer 0 (h0 = 0)
    ((h8*)hb[0])[tid] = h8{0, 0, 0, 0, 0, 0, 0, 0};
    __syncthreads();

    const size_t dirOff = (size_t)dir * HID;
    float pc[2][4], pn[2][4];
    auto preLoad = [&](int tc, float p[2][4]) {
#pragma unroll
        for (int jt = 0; jt < 2; ++jt) {
            int jc = j0 + jt * 16 + lj;
            size_t base = ((size_t)tc * BATCH + b0) * N2 + dirOff + jc;
#pragma unroll
            for (int i = 0; i < 4; ++i)
                p[jt][i] = (float)pre[base + (size_t)(lg * 4 + i) * N2];
        }
    };
    preLoad(dir ? (SEQL - 1) : 0, pc);

    for (int t = 0; t < SEQL; ++t) {
        if (t < SEQL - 1) {
            int tn = dir ? (SEQL - 2 - t) : (t + 1);
            preLoad(tn, pn);  // prefetch next step's pre tile
        }
        // A fragments: full h[16][256] (shared by both j-tiles)
        const char* hbc = (const char*)hb[t & 1];
        h8 af[8];
#pragma unroll
        for (int kk = 0; kk < 8; ++kk) {
            unsigned bo = (unsigned)lj * 512 + (((unsigned)(kk * 64 + lg * 16)) ^ ((lj & 7) << 4));
            af[kk] = *(const h8*)(hbc + bo);
        }
        f32x4 acc[2];
#pragma unroll
        for (int jt = 0; jt < 2; ++jt) acc[jt] = f32x4{pc[jt][0], pc[jt][1], pc[jt][2], pc[jt][3]};
#pragma unroll
        for (int kk = 0; kk < 8; ++kk) {
            acc[0] = __builtin_amdgcn_mfma_f32_16x16x32_f16(af[kk], bfrag[0][kk], acc[0], 0, 0, 0);
            acc[1] = __builtin_amdgcn_mfma_f32_16x16x32_f16(af[kk], bfrag[1][kk], acc[1], 0, 0, 0);
        }
        if (t < SEQL - 1) {
            char* ho = (char*)hb[(t & 1) ^ 1];
#pragma unroll
            for (int jt = 0; jt < 2; ++jt)
#pragma unroll
                for (int i = 0; i < 4; ++i) {
                    float v = ftanh(acc[jt][i]);
                    int rr = lg * 4 + i;
                    unsigned cc = (unsigned)(j0 + jt * 16 + lj);
                    *(_Float16*)(ho + rr * 512 + ((cc * 2) ^ ((rr & 7) << 4))) = (_Float16)v;
                }
            __syncthreads();
#pragma unroll
            for (int jt = 0; jt < 2; ++jt)
#pragma unroll
                for (int i = 0; i < 4; ++i) pc[jt][i] = pn[jt][i];
        } else {
#pragma unroll
            for (int jt = 0; jt < 2; ++jt)
#pragma unroll
                for (int i = 0; i < 4; ++i) {
                    float v = ftanh(acc[jt][i]);
                    hcat[(size_t)(b0 + lg * 4 + i) * N2 + dirOff + j0 + jt * 16 + lj] = v;
                }
        }
    }
}

// ---------------- head: per-batch-row MLP, fp32 VALU ----------------
__global__ __launch_bounds__(256) void head_mlp(
    const float* __restrict__ hcat,
    const float* __restrict__ fc1w, const float* __restrict__ fc1b,
    const float* __restrict__ fc2w, const float* __restrict__ fc2b,
    const float* __restrict__ fsw, const float* __restrict__ fsb,
    float* __restrict__ out)
{
    __shared__ float hs[512];
    __shared__ float y1[512];
    __shared__ float red[4];
    const int b = blockIdx.x, tid = threadIdx.x;
    hs[tid] = hcat[(size_t)b * N2 + tid];
    hs[tid + 256] = hcat[(size_t)b * N2 + 256 + tid];
    __syncthreads();
    float a0 = fc1b[tid], a1 = fc1b[tid + 256];
#pragma unroll 8
    for (int k = 0; k < 512; ++k) {
        float h = hs[k];
        a0 = fmaf(h, fc1w[(size_t)k * 512 + tid], a0);
        a1 = fmaf(h, fc1w[(size_t)k * 512 + tid + 256], a1);
    }
    y1[tid] = fmaxf(a0, 0.f);
    y1[tid + 256] = fmaxf(a1, 0.f);
    __syncthreads();
    float c0 = fc2b[tid];
#pragma unroll 8
    for (int k = 0; k < 512; ++k) c0 = fmaf(y1[k], fc2w[(size_t)k * 256 + tid], c0);
    float p = fmaxf(c0, 0.f) * fsw[tid];
#pragma unroll
    for (int off = 32; off > 0; off >>= 1) p += __shfl_down(p, off);
    if ((tid & 63) == 0) red[tid >> 6] = p;
    __syncthreads();
    if (tid == 0) out[b] = ftanh(red[0] + red[1] + red[2] + red[3] + fsb[0]);
}

extern "C" void kernel_launch(void* const* d_in, const int* in_sizes, int n_in,
                              void* d_out, int out_size, void* d_ws, size_t ws_size,
                              hipStream_t stream)
{
    const float* x    = (const float*)d_in[0];
    const float* W1x  = (const float*)d_in[1];
    const float* W1h  = (const float*)d_in[2];
    const float* b1   = (const float*)d_in[3];
    const float* W2x  = (const float*)d_in[4];
    const float* W2h  = (const float*)d_in[5];
    const float* b2   = (const float*)d_in[6];
    const float* fc1w = (const float*)d_in[7];
    const float* fc1b = (const float*)d_in[8];
    const float* fc2w = (const float*)d_in[9];
    const float* fc2b = (const float*)d_in[10];
    const float* fsw  = (const float*)d_in[11];
    const float* fsb  = (const float*)d_in[12];

    char* ws = (char*)d_ws;
    size_t off = 0;
    _Float16* WTs = (_Float16*)(ws + off); off += (size_t)N2 * KP * sizeof(_Float16); // 327,680
    float* bcat   = (float*)(ws + off);    off += (size_t)N2 * sizeof(float);          // +2,048
    float* hcat   = (float*)(ws + off);    off += (size_t)BATCH * N2 * sizeof(float);  // +524,288
    _Float16* pre = (_Float16*)(ws + off); off += (size_t)SEQL * BATCH * N2 * sizeof(_Float16); // +134,217,728
    if (off > ws_size) return;  // workspace insufficient -> fail loudly (poisoned out)

    prep_kernel<<<(N2 * KP + 255) / 256, 256, 0, stream>>>(W1x, W2x, b1, b2, WTs, bcat);
    gemm_pre<<<(SEQL * BATCH / 128) * (N2 / 128), 256, 0, stream>>>(x, WTs, bcat, pre);
    rnn_scan<<<(BATCH / 16) * 2, 512, 0, stream>>>(W1h, W2h, pre, hcat);
    head_mlp<<<BATCH, 256, 0, stream>>>(hcat, fc1w, fc1b, fc2w, fc2b, fsw, fsb, (float*)d_out);
}

// Round 2
// 659.280 us; speedup vs baseline: 1.0889x; 1.0889x over previous
//
#include <hip/hip_runtime.h>

#define DI __device__ __forceinline__

typedef float f32x4 __attribute__((ext_vector_type(4)));
typedef float f4    __attribute__((ext_vector_type(4)));
typedef _Float16 h8 __attribute__((ext_vector_type(8)));
typedef _Float16 h4 __attribute__((ext_vector_type(4)));

// sizes
#define SEQL 512
#define BATCH 256
#define INF 300
#define HID 256
#define N2 512   // 2*HID
#define KP 320   // INF padded to multiple of 64

DI float ftanh(float x) {
    float e = __expf(2.0f * x);
    return 1.0f - 2.0f / (e + 1.0f);
}

// ---------------- prep: build WcatT (pre-swizzled, f16) + bcat ----------------
__global__ void prep_kernel(const float* __restrict__ W1x, const float* __restrict__ W2x,
                            const float* __restrict__ b1, const float* __restrict__ b2,
                            _Float16* __restrict__ WTs, float* __restrict__ bcat)
{
    int idx = blockIdx.x * 256 + threadIdx.x;
    if (idx < N2 * KP) {
        int j = idx / KP, z = idx - j * KP;
        int k = z ^ ((j & 7) << 3);
        float v = 0.f;
        if (k < INF) v = (j < HID) ? W1x[k * HID + j] : W2x[k * HID + (j - HID)];
        WTs[j * KP + z] = (_Float16)v;
    }
    if (idx < N2) bcat[idx] = (idx < HID) ? b1[idx] : b2[idx - HID];
}

// ---------------- GEMM: pre[t*B+b][j] = x[t,b,:] @ Wcat[:,j] + bcat[j] ----------------
__global__ __launch_bounds__(256, 2) void gemm_pre(
    const float* __restrict__ x, const _Float16* __restrict__ WTs,
    const float* __restrict__ bcat, _Float16* __restrict__ pre)
{
    __shared__ _Float16 Ab[128 * 64];
    __shared__ _Float16 Bb[128 * 64];
    const int tid = threadIdx.x;
    const int w = tid >> 6, l = tid & 63;
    const int lj = l & 15, lg = l >> 4;
    const int bm = blockIdx.x >> 2, bn = blockIdx.x & 3;
    const size_t m0 = (size_t)bm * 128;
    const int j0 = bn * 128;
    const int wm = (w >> 1) * 64, wn = (w & 1) * 64;

    f32x4 acc[4][4];
#pragma unroll
    for (int a = 0; a < 4; ++a)
#pragma unroll
        for (int b = 0; b < 4; ++b) acc[a][b] = f32x4{0.f, 0.f, 0.f, 0.f};

    float bias[4];
#pragma unroll
    for (int nt = 0; nt < 4; ++nt) bias[nt] = bcat[j0 + wn + nt * 16 + lj];

    for (int s = 0; s < 5; ++s) {
        const int k0 = s * 64;
#pragma unroll
        for (int q = 0; q < 4; ++q) {
            int idx = (w * 4 + q) * 64 + l;
            int jr = idx >> 3, sl = idx & 7;
            const _Float16* src = WTs + (size_t)(j0 + jr) * KP + k0 + sl * 8;
            _Float16* dst = &Bb[(w * 4 + q) * 512];
            __builtin_amdgcn_global_load_lds(
                (const __attribute__((address_space(1))) void*)src,
                (__attribute__((address_space(3))) void*)dst, 16, 0, 0);
        }
#pragma unroll
        for (int c = 0; c < 8; ++c) {
            int f = c * 256 + tid;
            int mr = f >> 4, k4 = f & 15;
            f4 v;
            if (k0 + k4 * 4 + 3 < INF)
                v = *(const f4*)(x + (m0 + mr) * INF + k0 + k4 * 4);
            else
                v = f4{0.f, 0.f, 0.f, 0.f};
            unsigned bo = (unsigned)mr * 128 + (((unsigned)k4 * 8) ^ ((mr & 7) << 4));
            *(h4*)((char*)Ab + bo) = h4{(_Float16)v[0], (_Float16)v[1], (_Float16)v[2], (_Float16)v[3]};
        }
        __syncthreads();
#pragma unroll
        for (int kk = 0; kk < 2; ++kk) {
            h8 af[4], bf[4];
#pragma unroll
            for (int mt = 0; mt < 4; ++mt) {
                int mr = wm + mt * 16 + lj;
                unsigned bo = (unsigned)mr * 128 + (((unsigned)(kk * 64 + lg * 16)) ^ ((mr & 7) << 4));
                af[mt] = *(const h8*)((const char*)Ab + bo);
            }
#pragma unroll
            for (int nt = 0; nt < 4; ++nt) {
                int jr = wn + nt * 16 + lj;
                unsigned bo = (unsigned)jr * 128 + (((unsigned)(kk * 64 + lg * 16)) ^ ((jr & 7) << 4));
                bf[nt] = *(const h8*)((const char*)Bb + bo);
            }
#pragma unroll
            for (int mt = 0; mt < 4; ++mt)
#pragma unroll
                for (int nt = 0; nt < 4; ++nt)
                    acc[mt][nt] = __builtin_amdgcn_mfma_f32_16x16x32_f16(af[mt], bf[nt], acc[mt][nt], 0, 0, 0);
        }
        __syncthreads();
    }
#pragma unroll
    for (int mt = 0; mt < 4; ++mt) {
#pragma unroll
        for (int nt = 0; nt < 4; ++nt) {
            int jc = j0 + wn + nt * 16 + lj;
#pragma unroll
            for (int i = 0; i < 4; ++i) {
                size_t r = m0 + wm + mt * 16 + lg * 4 + i;
                pre[r * N2 + jc] = (_Float16)(acc[mt][nt][i] + bias[nt]);
            }
        }
    }
}

// ---------------- recurrence: swapped-operand MFMA (D = WhT * hT) ----------------
// 32 blocks = 16 b-tiles x 2 dirs, 8 waves each. h kept in LDS [b][k] f16, XOR-swizzled,
// double-buffered. Output fragment row=j, col=b -> vector pre-loads, vector h-writes.
__global__ __launch_bounds__(512, 2) void rnn_scan(
    const float* __restrict__ W1h, const float* __restrict__ W2h,
    const _Float16* __restrict__ pre, float* __restrict__ hcat)
{
    __shared__ _Float16 hb[2][16 * 256];
    const int tid = threadIdx.x;
    const int w = tid >> 6, l = tid & 63;
    const int lj = l & 15, lg = l >> 4;
    const int dir = blockIdx.x & 1;
    const int b0 = (int)(blockIdx.x >> 1) * 16;
    const float* Wh = dir ? W2h : W1h;
    const int j0 = w * 32;
    const int dirOff = dir ? HID : 0;

    // A = Wh^T fragments (constant across all 512 steps): lane l holds
    // A[row=j0+jt*16+(l&15)][k=kk*32+(l>>4)*8+i] = Wh[k][j]
    h8 afrag[2][8];
#pragma unroll
    for (int jt = 0; jt < 2; ++jt) {
        int jc = j0 + jt * 16 + lj;
#pragma unroll
        for (int kk = 0; kk < 8; ++kk) {
            h8 t;
#pragma unroll
            for (int i = 0; i < 8; ++i) t[i] = (_Float16)Wh[(kk * 32 + lg * 8 + i) * HID + jc];
            afrag[jt][kk] = t;
        }
    }

    // precomputed LDS byte addresses (zero per-step address VALU)
    char* hbc = (char*)hb;
    unsigned ra[8];
#pragma unroll
    for (int kk = 0; kk < 8; ++kk)
        ra[kk] = (unsigned)lj * 512 + (((unsigned)(kk * 64 + lg * 16)) ^ ((unsigned)(lj & 7) << 4));
    unsigned wa[2];
#pragma unroll
    for (int jt = 0; jt < 2; ++jt)
        wa[jt] = (unsigned)lj * 512 + (((unsigned)(w * 64 + jt * 32 + lg * 8)) ^ ((unsigned)(lj & 7) << 4));

    // H(0) = 0 in buf0
    ((h8*)hb[0])[tid] = h8{0, 0, 0, 0, 0, 0, 0, 0};
    __syncthreads();

    // pre stream: lane loads pre[t][b0+lj][dirOff + j0 + jt*16 + lg*4 .. +3], prefetch depth 2
    const long long sstride = dir ? -(long long)(BATCH * N2) : (long long)(BATCH * N2);
    const int t0 = dir ? (SEQL - 1) : 0;
    const _Float16* pp = pre + (long long)t0 * BATCH * N2
                       + (long long)(b0 + lj) * N2 + dirOff + j0 + lg * 4;
    h4 pA0, pA1, pB0, pB1;
    pA0 = *(const h4*)pp; pA1 = *(const h4*)(pp + 16); pp += sstride;
    pB0 = *(const h4*)pp; pB1 = *(const h4*)(pp + 16); pp += sstride;

#define RNN_STEP(ROFF, WOFF, P0, P1, DO_PF)                                           \
    do {                                                                              \
        f32x4 acc0, acc1;                                                             \
        _Pragma("unroll")                                                             \
        for (int i = 0; i < 4; ++i) { acc0[i] = (float)P0[i]; acc1[i] = (float)P1[i]; } \
        if (DO_PF) { P0 = *(const h4*)pp; P1 = *(const h4*)(pp + 16); pp += sstride; } \
        h8 bf[8];                                                                     \
        _Pragma("unroll")                                                             \
        for (int kk = 0; kk < 8; ++kk) bf[kk] = *(const h8*)(hbc + (ROFF) + ra[kk]);  \
        _Pragma("unroll")                                                             \
        for (int kk = 0; kk < 8; ++kk) {                                              \
            acc0 = __builtin_amdgcn_mfma_f32_16x16x32_f16(afrag[0][kk], bf[kk], acc0, 0, 0, 0); \
            acc1 = __builtin_amdgcn_mfma_f32_16x16x32_f16(afrag[1][kk], bf[kk], acc1, 0, 0, 0); \
        }                                                                             \
        h4 o0, o1;                                                                    \
        _Pragma("unroll")                                                             \
        for (int i = 0; i < 4; ++i) {                                                 \
            o0[i] = (_Float16)ftanh(acc0[i]);                                         \
            o1[i] = (_Float16)ftanh(acc1[i]);                                         \
        }                                                                             \
        *(h4*)(hbc + (WOFF) + wa[0]) = o0;                                            \
        *(h4*)(hbc + (WOFF) + wa[1]) = o1;                                            \
        __builtin_amdgcn_sched_barrier(0);                                            \
        asm volatile("s_waitcnt lgkmcnt(0)" ::: "memory");                            \
        __builtin_amdgcn_s_barrier();                                                 \
        __builtin_amdgcn_sched_barrier(0);                                            \
    } while (0)

    // steps 0..509 (255 unrolled pairs); prefetch loads through t=511 (never OOB)
    for (int tp = 0; tp < 255; ++tp) {
        RNN_STEP(0, 8192, pA0, pA1, 1);
        RNN_STEP(8192, 0, pB0, pB1, 1);
    }
    // step 510: read buf0, write buf1, no prefetch
    RNN_STEP(0, 8192, pA0, pA1, 0);

    // step 511: read buf1, write hcat (f32, coalesced float4)
    {
        f32x4 acc0, acc1;
#pragma unroll
        for (int i = 0; i < 4; ++i) { acc0[i] = (float)pB0[i]; acc1[i] = (float)pB1[i]; }
        h8 bf[8];
#pragma unroll
        for (int kk = 0; kk < 8; ++kk) bf[kk] = *(const h8*)(hbc + 8192 + ra[kk]);
#pragma unroll
        for (int kk = 0; kk < 8; ++kk) {
            acc0 = __builtin_amdgcn_mfma_f32_16x16x32_f16(afrag[0][kk], bf[kk], acc0, 0, 0, 0);
            acc1 = __builtin_amdgcn_mfma_f32_16x16x32_f16(afrag[1][kk], bf[kk], acc1, 0, 0, 0);
        }
        f4 v0, v1;
#pragma unroll
        for (int i = 0; i < 4; ++i) { v0[i] = ftanh(acc0[i]); v1[i] = ftanh(acc1[i]); }
        float* hc = hcat + (size_t)(b0 + lj) * N2 + dirOff + j0 + lg * 4;
        *(f4*)hc = v0;
        *(f4*)(hc + 16) = v1;
    }
#undef RNN_STEP
}

// ---------------- head: per-batch-row MLP, fp32 VALU ----------------
__global__ __launch_bounds__(256) void head_mlp(
    const float* __restrict__ hcat,
    const float* __restrict__ fc1w, const float* __restrict__ fc1b,
    const float* __restrict__ fc2w, const float* __restrict__ fc2b,
    const float* __restrict__ fsw, const float* __restrict__ fsb,
    float* __restrict__ out)
{
    __shared__ float hs[512];
    __shared__ float y1[512];
    __shared__ float red[4];
    const int b = blockIdx.x, tid = threadIdx.x;
    hs[tid] = hcat[(size_t)b * N2 + tid];
    hs[tid + 256] = hcat[(size_t)b * N2 + 256 + tid];
    __syncthreads();
    float a0 = fc1b[tid], a1 = fc1b[tid + 256];
#pragma unroll 8
    for (int k = 0; k < 512; ++k) {
        float h = hs[k];
        a0 = fmaf(h, fc1w[(size_t)k * 512 + tid], a0);
        a1 = fmaf(h, fc1w[(size_t)k * 512 + tid + 256], a1);
    }
    y1[tid] = fmaxf(a0, 0.f);
    y1[tid + 256] = fmaxf(a1, 0.f);
    __syncthreads();
    float c0 = fc2b[tid];
#pragma unroll 8
    for (int k = 0; k < 512; ++k) c0 = fmaf(y1[k], fc2w[(size_t)k * 256 + tid], c0);
    float p = fmaxf(c0, 0.f) * fsw[tid];
#pragma unroll
    for (int off = 32; off > 0; off >>= 1) p += __shfl_down(p, off);
    if ((tid & 63) == 0) red[tid >> 6] = p;
    __syncthreads();
    if (tid == 0) out[b] = ftanh(red[0] + red[1] + red[2] + red[3] + fsb[0]);
}

extern "C" void kernel_launch(void* const* d_in, const int* in_sizes, int n_in,
                              void* d_out, int out_size, void* d_ws, size_t ws_size,
                              hipStream_t stream)
{
    const float* x    = (const float*)d_in[0];
    const float* W1x  = (const float*)d_in[1];
    const float* W1h  = (const float*)d_in[2];
    const float* b1   = (const float*)d_in[3];
    const float* W2x  = (const float*)d_in[4];
    const float* W2h  = (const float*)d_in[5];
    const float* b2   = (const float*)d_in[6];
    const float* fc1w = (const float*)d_in[7];
    const float* fc1b = (const float*)d_in[8];
    const float* fc2w = (const float*)d_in[9];
    const float* fc2b = (const float*)d_in[10];
    const float* fsw  = (const float*)d_in[11];
    const float* fsb  = (const float*)d_in[12];

    char* ws = (char*)d_ws;
    size_t off = 0;
    _Float16* WTs = (_Float16*)(ws + off); off += (size_t)N2 * KP * sizeof(_Float16);
    float* bcat   = (float*)(ws + off);    off += (size_t)N2 * sizeof(float);
    float* hcat   = (float*)(ws + off);    off += (size_t)BATCH * N2 * sizeof(float);
    _Float16* pre = (_Float16*)(ws + off); off += (size_t)SEQL * BATCH * N2 * sizeof(_Float16);
    if (off > ws_size) return;

    prep_kernel<<<(N2 * KP + 255) / 256, 256, 0, stream>>>(W1x, W2x, b1, b2, WTs, bcat);
    gemm_pre<<<(SEQL * BATCH / 128) * (N2 / 128), 256, 0, stream>>>(x, WTs, bcat, pre);
    rnn_scan<<<(BATCH / 16) * 2, 512, 0, stream>>>(W1h, W2h, pre, hcat);
    head_mlp<<<BATCH, 256, 0, stream>>>(hcat, fc1w, fc1b, fc2w, fc2b, fsw, fsb, (float*)d_out);
}